// Round 1
// baseline (5918.743 us; speedup 1.0000x reference)
//
#include <hip/hip_runtime.h>
#include <stdint.h>

#define B_ 2
#define C_ 64
#define T_ 3000
#define F_ 65
#define H_ 4
#define D_ 4
#define E_ 16
#define TF_ (T_*F_)          // 195000
#define NPT (B_*TF_)         // 390000
#define DQK 260              // D*F
#define DQKP 288             // padded to multiple of 32 (future MFMA K-dim)
#define EF 1040              // E*F

typedef unsigned short u16;
typedef unsigned int   u32;

__device__ __forceinline__ float bf2f(u16 u){ return __uint_as_float(((u32)u)<<16); }
__device__ __forceinline__ u16 f2bf(float f){
  u32 u = __float_as_uint(f);
  u32 r = u + 0x7fffu + ((u>>16)&1u);   // RNE
  return (u16)(r>>16);
}

// ---------------------------------------------------------------------------
// K1: per-head 1x1 conv Q/K/V + PReLU + channel-LN -> bf16 Qf/Kf (padded 288), Vf
// one thread per (b,t,f) point; 96 fp32 accumulators; weights in LDS as float4
// ---------------------------------------------------------------------------
__global__ __launch_bounds__(256) void qkv_kernel(
    const float* __restrict__ x,
    const float* __restrict__ Wq, const float* __restrict__ bq, const float* __restrict__ aq,
    const float* __restrict__ gq, const float* __restrict__ bteq,
    const float* __restrict__ Wk, const float* __restrict__ bk, const float* __restrict__ ak,
    const float* __restrict__ gk, const float* __restrict__ btek,
    const float* __restrict__ Wv, const float* __restrict__ bv, const float* __restrict__ av,
    const float* __restrict__ gv, const float* __restrict__ btev,
    u16* __restrict__ Qf, u16* __restrict__ Kf, u16* __restrict__ Vf)
{
  __shared__ __align__(16) float4 w4[1536];   // Wq(256) Wk(256) Wv(1024) as float4
  __shared__ float prm[304];
  const int tid = threadIdx.x;
  {
    const float4* a = (const float4*)Wq;
    const float4* b = (const float4*)Wk;
    const float4* c = (const float4*)Wv;
    for (int i = tid; i < 1536; i += 256)
      w4[i] = (i < 256) ? a[i] : (i < 512) ? b[i-256] : c[i-512];
    for (int i = tid; i < 304; i += 256) {
      float v = 0.f;
      if      (i < 16)  v = bq[i];
      else if (i < 20)  v = aq[i-16];
      else if (i < 36)  v = gq[i-20];
      else if (i < 52)  v = bteq[i-36];
      else if (i < 68)  v = bk[i-52];
      else if (i < 72)  v = ak[i-68];
      else if (i < 88)  v = gk[i-72];
      else if (i < 104) v = btek[i-88];
      else if (i < 168) v = bv[i-104];
      else if (i < 172) v = av[i-168];
      else if (i < 236) v = gv[i-172];
      else if (i < 300) v = btev[i-236];
      prm[i] = v;
    }
  }
  __syncthreads();
  const int p = blockIdx.x*256 + tid;
  if (p >= NPT) return;
  const int b = p / TF_;
  const int r = p - b*TF_;
  const int t = r / F_;
  const int f = r - t*F_;
  const float* xb = x + (size_t)b*C_*TF_ + r;

  float accq[16], acck[16], accv[64];
  #pragma unroll
  for (int i=0;i<16;i++){ accq[i]=0.f; acck[i]=0.f; }
  #pragma unroll
  for (int i=0;i<64;i++) accv[i]=0.f;

  for (int c4 = 0; c4 < 16; ++c4) {
    const float x0 = xb[(size_t)(c4*4+0)*TF_];
    const float x1 = xb[(size_t)(c4*4+1)*TF_];
    const float x2 = xb[(size_t)(c4*4+2)*TF_];
    const float x3 = xb[(size_t)(c4*4+3)*TF_];
    #pragma unroll
    for (int o=0;o<16;o++){
      float4 w = w4[o*16+c4];
      accq[o] = fmaf(w.w,x3,fmaf(w.z,x2,fmaf(w.y,x1,fmaf(w.x,x0,accq[o]))));
    }
    #pragma unroll
    for (int o=0;o<16;o++){
      float4 w = w4[256+o*16+c4];
      acck[o] = fmaf(w.w,x3,fmaf(w.z,x2,fmaf(w.y,x1,fmaf(w.x,x0,acck[o]))));
    }
    #pragma unroll
    for (int o=0;o<64;o++){
      float4 w = w4[512+o*16+c4];
      accv[o] = fmaf(w.w,x3,fmaf(w.z,x2,fmaf(w.y,x1,fmaf(w.x,x0,accv[o]))));
    }
  }

  #pragma unroll
  for (int h=0; h<H_; h++){
    { // Q: bias, PReLU, LN over D=4
      float v[4]; float s = 0.f;
      #pragma unroll
      for (int d=0; d<4; d++){
        float a = accq[h*4+d] + prm[h*4+d];
        a = (a >= 0.f) ? a : prm[16+h]*a;
        v[d] = a; s += a;
      }
      float mu = s * 0.25f;
      float var = 0.f;
      #pragma unroll
      for (int d=0; d<4; d++){ float dd = v[d]-mu; var = fmaf(dd,dd,var); }
      var *= 0.25f;
      float rs = rsqrtf(var + 1e-5f);
      u16* qrow = Qf + ((size_t)(b*H_+h)*T_ + t)*DQKP + f;
      #pragma unroll
      for (int d=0; d<4; d++)
        qrow[d*F_] = f2bf((v[d]-mu)*rs*prm[20+h*4+d] + prm[36+h*4+d]);
    }
    { // K
      float v[4]; float s = 0.f;
      #pragma unroll
      for (int d=0; d<4; d++){
        float a = acck[h*4+d] + prm[52+h*4+d];
        a = (a >= 0.f) ? a : prm[68+h]*a;
        v[d] = a; s += a;
      }
      float mu = s * 0.25f;
      float var = 0.f;
      #pragma unroll
      for (int d=0; d<4; d++){ float dd = v[d]-mu; var = fmaf(dd,dd,var); }
      var *= 0.25f;
      float rs = rsqrtf(var + 1e-5f);
      u16* krow = Kf + ((size_t)(b*H_+h)*T_ + t)*DQKP + f;
      #pragma unroll
      for (int d=0; d<4; d++)
        krow[d*F_] = f2bf((v[d]-mu)*rs*prm[72+h*4+d] + prm[88+h*4+d]);
    }
    { // V: LN over E=16
      float v[16]; float s = 0.f;
      #pragma unroll
      for (int e=0; e<16; e++){
        float a = accv[h*16+e] + prm[104+h*16+e];
        a = (a >= 0.f) ? a : prm[168+h]*a;
        v[e] = a; s += a;
      }
      float mu = s * (1.f/16.f);
      float var = 0.f;
      #pragma unroll
      for (int e=0; e<16; e++){ float dd = v[e]-mu; var = fmaf(dd,dd,var); }
      var *= (1.f/16.f);
      float rs = rsqrtf(var + 1e-5f);
      u16* vrow = Vf + ((size_t)(b*H_+h)*T_ + t)*EF + f;
      #pragma unroll
      for (int e=0; e<16; e++)
        vrow[e*F_] = f2bf((v[e]-mu)*rs*prm[172+h*16+e] + prm[236+h*16+e]);
    }
  }
  if (f < DQKP - DQK) {   // zero the 28 pad columns (future MFMA K-dim)
    #pragma unroll
    for (int h=0; h<H_; h++){
      size_t idx = ((size_t)(b*H_+h)*T_ + t)*DQKP + DQK + f;
      Qf[idx] = 0; Kf[idx] = 0;
    }
  }
}

// ---------------------------------------------------------------------------
// K2: flash attention (online softmax), fp32 vector math on bf16 operands.
// block=512 (8 waves), qtile=32 rows, ktile=64. K tile and V chunks share one
// LDS union; V is staged so each block reads each V tile exactly once.
// Score mapping: lane=s, wave w owns rows {w,w+8,w+16,w+24}.
// PV  mapping: wave w owns rows {4w..4w+3}; lane owns col pairs 2l+128*jj.
// ---------------------------------------------------------------------------
__global__ __launch_bounds__(512) void attn_kernel(
    const u16* __restrict__ Qf, const u16* __restrict__ Kf,
    const u16* __restrict__ Vf, float* __restrict__ Oo)
{
  __shared__ __align__(16) u16   q_lds[32*260];     // 16,640 B
  __shared__ __align__(16) u16   kv_lds[64*268];    // 34,304 B (K stride 268 / V stride 256)
  __shared__ __align__(16) float p_lds[64*36];      //  9,216 B (P^T, padded stride)
  __shared__ __align__(16) float alpha_lds[32];
  __shared__ __align__(16) float l_lds[32];

  const int tid = threadIdx.x;
  const int w = tid >> 6;
  const int l = tid & 63;
  const int bh = blockIdx.y;
  const int r0 = blockIdx.x * 32;

  const u16* Qb = Qf + (size_t)bh*T_*DQKP;
  const u16* Kb = Kf + (size_t)bh*T_*DQKP;
  const u16* Vb = Vf + (size_t)bh*T_*EF;

  // stage Q tile (bf16, 260 live cols)
  for (int i = tid; i < 32*65; i += 512) {
    int row = i / 65;
    int c4 = (i - row*65) * 4;
    int gr = r0 + row; gr = (gr < T_) ? gr : (T_-1);
    *(ushort4*)(q_lds + row*260 + c4) = *(const ushort4*)(Qb + (size_t)gr*DQKP + c4);
  }

  float m_i[4], l_i[4];
  #pragma unroll
  for (int i=0;i<4;i++){ m_i[i] = -3.0e38f; l_i[i] = 0.f; }
  float acc[4][9][2];
  #pragma unroll
  for (int a=0;a<4;a++){
    #pragma unroll
    for (int jj=0;jj<9;jj++){ acc[a][jj][0]=0.f; acc[a][jj][1]=0.f; }
  }

  const float scale = 0.062017367294604234f;   // 1/sqrt(260)

  for (int kt = 0; kt < 47; ++kt) {
    const int s0 = kt * 64;
    __syncthreads();                            // kv_lds / p_lds free for reuse
    // stage K tile (stride 268 breaks worst bank aliasing)
    for (int i = tid; i < 64*65; i += 512) {
      int row = i / 65;
      int c4 = (i - row*65) * 4;
      int gs = s0 + row; gs = (gs < T_) ? gs : (T_-1);
      *(ushort4*)(kv_lds + row*268 + c4) = *(const ushort4*)(Kb + (size_t)gs*DQKP + c4);
    }
    __syncthreads();

    // scores: 4 rows per thread, s = lane
    float sacc[4] = {0.f,0.f,0.f,0.f};
    for (int c4 = 0; c4 < 65; ++c4) {
      ushort4 kv = *(const ushort4*)(kv_lds + l*268 + c4*4);
      float k0 = bf2f(kv.x), k1 = bf2f(kv.y), k2 = bf2f(kv.z), k3 = bf2f(kv.w);
      #pragma unroll
      for (int i=0;i<4;i++){
        ushort4 qv = *(const ushort4*)(q_lds + (w + 8*i)*260 + c4*4);
        sacc[i] = fmaf(bf2f(qv.w),k3,fmaf(bf2f(qv.z),k2,
                  fmaf(bf2f(qv.y),k1,fmaf(bf2f(qv.x),k0,sacc[i]))));
      }
    }
    const bool svalid = (s0 + l) < T_;
    #pragma unroll
    for (int i=0;i<4;i++){
      float sv = svalid ? sacc[i]*scale : -3.0e38f;
      float tmax = sv;
      #pragma unroll
      for (int off=32; off>0; off>>=1) tmax = fmaxf(tmax, __shfl_xor(tmax, off));
      float mnew = fmaxf(m_i[i], tmax);
      float alpha = __expf(m_i[i] - mnew);
      float pv = __expf(sv - mnew);              // masked lanes -> exp(-huge) = 0
      float tsum = pv;
      #pragma unroll
      for (int off=32; off>0; off>>=1) tsum += __shfl_xor(tsum, off);
      l_i[i] = l_i[i]*alpha + tsum;
      m_i[i] = mnew;
      p_lds[l*36 + (w + 8*i)] = pv;              // P^T[s][r]
      if (l == 0) { alpha_lds[w + 8*i] = alpha; l_lds[w + 8*i] = l_i[i]; }
    }
    __syncthreads();                             // P/alpha ready; K reads done

    { // rescale running O by alpha (rows 4w..4w+3)
      const float4 a4 = *(const float4*)(alpha_lds + 4*w);
      const float ar[4] = {a4.x, a4.y, a4.z, a4.w};
      #pragma unroll
      for (int ii=0;ii<4;ii++){
        #pragma unroll
        for (int jj=0;jj<9;jj++){ acc[ii][jj][0]*=ar[ii]; acc[ii][jj][1]*=ar[ii]; }
      }
    }

    // PV: V staged in 256-col chunks into the kv union
    #pragma unroll
    for (int jc = 0; jc < 5; ++jc) {
      const int nch = (jc < 4) ? 32 : 2;         // 16B chunks per row
      if (jc) __syncthreads();
      for (int i = tid; i < 64*nch; i += 512) {
        int row = i / nch;
        int c8 = (i - row*nch) * 8;
        int gs = s0 + row; gs = (gs < T_) ? gs : (T_-1);
        *(uint4*)(kv_lds + row*256 + c8) = *(const uint4*)(Vb + (size_t)gs*EF + jc*256 + c8);
      }
      __syncthreads();
      const int numu = (jc < 4) ? 2 : 1;
      for (int s = 0; s < 64; ++s) {
        const float4 p4 = *(const float4*)(p_lds + s*36 + 4*w);
        #pragma unroll
        for (int u = 0; u < numu; ++u) {
          if (jc < 4 || l < 8) {
            u32 vv = *(const u32*)(kv_lds + s*256 + u*128 + 2*l);
            float f0 = __uint_as_float(vv << 16);
            float f1 = __uint_as_float(vv & 0xffff0000u);
            const int jj = jc*2 + u;
            acc[0][jj][0] = fmaf(p4.x, f0, acc[0][jj][0]);
            acc[0][jj][1] = fmaf(p4.x, f1, acc[0][jj][1]);
            acc[1][jj][0] = fmaf(p4.y, f0, acc[1][jj][0]);
            acc[1][jj][1] = fmaf(p4.y, f1, acc[1][jj][1]);
            acc[2][jj][0] = fmaf(p4.z, f0, acc[2][jj][0]);
            acc[2][jj][1] = fmaf(p4.z, f1, acc[2][jj][1]);
            acc[3][jj][0] = fmaf(p4.w, f0, acc[3][jj][0]);
            acc[3][jj][1] = fmaf(p4.w, f1, acc[3][jj][1]);
          }
        }
      }
    }
  }

  // epilogue: divide by l, store O
  const float4 l4 = *(const float4*)(l_lds + 4*w);
  const float li[4] = {1.f/l4.x, 1.f/l4.y, 1.f/l4.z, 1.f/l4.w};
  #pragma unroll
  for (int ii=0; ii<4; ii++){
    const int rr = r0 + 4*w + ii;
    if (rr < T_) {
      float* orow = Oo + ((size_t)bh*T_ + rr)*EF;
      #pragma unroll
      for (int jj=0; jj<9; jj++){
        if (jj < 8 || l < 8) {
          float2 st; st.x = acc[ii][jj][0]*li[ii]; st.y = acc[ii][jj][1]*li[ii];
          *(float2*)(orow + 2*l + 128*jj) = st;
        }
      }
    }
  }
}

// ---------------------------------------------------------------------------
// K3: final 1x1 conv (64x64) + PReLU + LN over C + residual
// ---------------------------------------------------------------------------
__global__ __launch_bounds__(256) void outp_kernel(
    const float* __restrict__ Oo, const float* __restrict__ x,
    const float* __restrict__ Wp, const float* __restrict__ bp, const float* __restrict__ ap,
    const float* __restrict__ gp, const float* __restrict__ btep,
    float* __restrict__ out)
{
  __shared__ __align__(16) float4 wp4[1024];
  __shared__ float prm[193];
  const int tid = threadIdx.x;
  {
    const float4* wp = (const float4*)Wp;
    for (int i = tid; i < 1024; i += 256) wp4[i] = wp[i];
    if (tid < 193) {
      float v;
      if      (tid < 64)  v = bp[tid];
      else if (tid < 128) v = gp[tid-64];
      else if (tid < 192) v = btep[tid-128];
      else                v = ap[0];
      prm[tid] = v;
    }
  }
  __syncthreads();
  const int p = blockIdx.x*256 + tid;
  if (p >= NPT) return;
  const int b = p / TF_;
  const int r = p - b*TF_;
  const int t = r / F_;
  const int f = r - t*F_;

  float4 ov[16];   // 64 attention-output channels, c = h*16 + e
  #pragma unroll
  for (int h=0; h<4; h++){
    const float* ob = Oo + ((size_t)(b*H_+h)*T_ + t)*EF + f;
    #pragma unroll
    for (int e4=0; e4<4; e4++){
      float4 vv;
      vv.x = ob[(e4*4+0)*F_];
      vv.y = ob[(e4*4+1)*F_];
      vv.z = ob[(e4*4+2)*F_];
      vv.w = ob[(e4*4+3)*F_];
      ov[h*4+e4] = vv;
    }
  }
  const float apv = prm[192];
  float y[64];
  float ssum = 0.f, ssq = 0.f;
  #pragma unroll
  for (int o=0; o<64; o++){
    float a = prm[o];
    #pragma unroll
    for (int c4=0; c4<16; c4++){
      float4 wv = wp4[o*16+c4];
      float4 xv = ov[c4];
      a = fmaf(wv.w,xv.w,fmaf(wv.z,xv.z,fmaf(wv.y,xv.y,fmaf(wv.x,xv.x,a))));
    }
    a = (a >= 0.f) ? a : apv*a;
    y[o] = a; ssum += a; ssq = fmaf(a,a,ssq);
  }
  const float mu = ssum * (1.f/64.f);
  const float var = ssq * (1.f/64.f) - mu*mu;
  const float rs = rsqrtf(var + 1e-5f);
  const float* xb = x + (size_t)b*C_*TF_ + r;
  float* yb = out + (size_t)b*C_*TF_ + r;
  #pragma unroll
  for (int o=0; o<64; o++){
    yb[(size_t)o*TF_] = fmaf((y[o]-mu)*rs, prm[64+o], prm[128+o]) + xb[(size_t)o*TF_];
  }
}

// ---------------------------------------------------------------------------
extern "C" void kernel_launch(void* const* d_in, const int* in_sizes, int n_in,
                              void* d_out, int out_size, void* d_ws, size_t ws_size,
                              hipStream_t stream)
{
  const float* x    = (const float*)d_in[0];
  const float* Wq   = (const float*)d_in[1];
  const float* bq   = (const float*)d_in[2];
  const float* aq   = (const float*)d_in[3];
  const float* gq   = (const float*)d_in[4];
  const float* bteq = (const float*)d_in[5];
  const float* Wk   = (const float*)d_in[6];
  const float* bk   = (const float*)d_in[7];
  const float* ak   = (const float*)d_in[8];
  const float* gk   = (const float*)d_in[9];
  const float* btek = (const float*)d_in[10];
  const float* Wv   = (const float*)d_in[11];
  const float* bv   = (const float*)d_in[12];
  const float* av   = (const float*)d_in[13];
  const float* gv   = (const float*)d_in[14];
  const float* btev = (const float*)d_in[15];
  const float* Wp   = (const float*)d_in[16];
  const float* bp   = (const float*)d_in[17];
  const float* ap   = (const float*)d_in[18];
  const float* gp   = (const float*)d_in[19];
  const float* btep = (const float*)d_in[20];

  // workspace layout (bytes):
  //   Qf bf16 [2,4,3000,288]  @ 0          (13,824,000)
  //   Kf bf16 [2,4,3000,288]  @ 13,824,000 (13,824,000)
  //   Vf bf16 [2,4,3000,1040] @ 27,648,000 (49,920,000)
  //   Oo fp32 [2,4,3000,1040] @ 77,568,000 (99,840,000)  -> total 177,408,000 B
  u16* Qf = (u16*)d_ws;
  u16* Kf = Qf + (size_t)B_*H_*T_*DQKP;
  u16* Vf = Kf + (size_t)B_*H_*T_*DQKP;
  float* Oo = (float*)((char*)d_ws + 77568000);
  float* out = (float*)d_out;

  qkv_kernel<<<dim3((NPT+255)/256), dim3(256), 0, stream>>>(
      x, Wq,bq,aq,gq,bteq, Wk,bk,ak,gk,btek, Wv,bv,av,gv,btev, Qf,Kf,Vf);
  attn_kernel<<<dim3(94, 8), dim3(512), 0, stream>>>(Qf, Kf, Vf, Oo);
  outp_kernel<<<dim3((NPT+255)/256), dim3(256), 0, stream>>>(
      Oo, x, Wp,bp,ap,gp,btep, out);
}

// Round 2
// 1005.304 us; speedup vs baseline: 5.8875x; 5.8875x over previous
//
#include <hip/hip_runtime.h>
#include <stdint.h>

#define B_ 2
#define C_ 64
#define T_ 3000
#define F_ 65
#define H_ 4
#define D_ 4
#define E_ 16
#define TF_ (T_*F_)          // 195000
#define NPT (B_*TF_)         // 390000
#define EF 1040              // E*F
#define TP 3072              // padded T for GEMM row/col blocks (24*128)
#define TK 3008              // padded key dim for Vt (47*64)
#define DQK 260              // D*F (live Q/K cols)
#define SQK 328              // Q/K global row stride (bank-friendly, 9*32=288 read)
#define VTROWS 1152          // padded V cols (9*128)

typedef unsigned short u16;
typedef unsigned int   u32;
typedef __attribute__((ext_vector_type(8))) short  s16x8;
typedef __attribute__((ext_vector_type(4))) float  f32x4;

__device__ __forceinline__ float bf2f(u16 u){ return __uint_as_float(((u32)u)<<16); }
__device__ __forceinline__ u16 f2bf(float f){
  u32 u = __float_as_uint(f);
  u32 r = u + 0x7fffu + ((u>>16)&1u);   // RNE
  return (u16)(r>>16);
}

__device__ __forceinline__ void gld16(const u16* g, u16* l){
  __builtin_amdgcn_global_load_lds((const __attribute__((address_space(1))) u32*)g,
                                   (__attribute__((address_space(3))) u32*)l,
                                   16, 0, 0);
}

// ---------------------------------------------------------------------------
// K1: per-head 1x1 conv Q/K/V + PReLU + channel-LN
//  -> Qf/Kf bf16 [8][3072][328] (rows 3000.., cols 260.. left as-is; harmless)
//  -> Vf bf16 [8][3000][1040]
//  also zeroes lbuf[8*3072]
// ---------------------------------------------------------------------------
__global__ __launch_bounds__(256) void qkv_kernel(
    const float* __restrict__ x,
    const float* __restrict__ Wq, const float* __restrict__ bq, const float* __restrict__ aq,
    const float* __restrict__ gq, const float* __restrict__ bteq,
    const float* __restrict__ Wk, const float* __restrict__ bk, const float* __restrict__ ak,
    const float* __restrict__ gk, const float* __restrict__ btek,
    const float* __restrict__ Wv, const float* __restrict__ bv, const float* __restrict__ av,
    const float* __restrict__ gv, const float* __restrict__ btev,
    u16* __restrict__ Qf, u16* __restrict__ Kf, u16* __restrict__ Vf,
    float* __restrict__ lbuf)
{
  __shared__ __align__(16) float4 w4[1536];   // Wq(256) Wk(256) Wv(1024) as float4
  __shared__ float prm[304];
  const int tid = threadIdx.x;
  {
    const float4* a = (const float4*)Wq;
    const float4* b = (const float4*)Wk;
    const float4* c = (const float4*)Wv;
    for (int i = tid; i < 1536; i += 256)
      w4[i] = (i < 256) ? a[i] : (i < 512) ? b[i-256] : c[i-512];
    for (int i = tid; i < 304; i += 256) {
      float v = 0.f;
      if      (i < 16)  v = bq[i];
      else if (i < 20)  v = aq[i-16];
      else if (i < 36)  v = gq[i-20];
      else if (i < 52)  v = bteq[i-36];
      else if (i < 68)  v = bk[i-52];
      else if (i < 72)  v = ak[i-68];
      else if (i < 88)  v = gk[i-72];
      else if (i < 104) v = btek[i-88];
      else if (i < 168) v = bv[i-104];
      else if (i < 172) v = av[i-168];
      else if (i < 236) v = gv[i-172];
      else if (i < 300) v = btev[i-236];
      prm[i] = v;
    }
  }
  const int p = blockIdx.x*256 + tid;
  if (p < 8*TP) lbuf[p] = 0.f;   // zero the softmax-denominator accumulator
  __syncthreads();
  if (p >= NPT) return;
  const int b = p / TF_;
  const int r = p - b*TF_;
  const int t = r / F_;
  const int f = r - t*F_;
  const float* xb = x + (size_t)b*C_*TF_ + r;

  float accq[16], acck[16], accv[64];
  #pragma unroll
  for (int i=0;i<16;i++){ accq[i]=0.f; acck[i]=0.f; }
  #pragma unroll
  for (int i=0;i<64;i++) accv[i]=0.f;

  for (int c4 = 0; c4 < 16; ++c4) {
    const float x0 = xb[(size_t)(c4*4+0)*TF_];
    const float x1 = xb[(size_t)(c4*4+1)*TF_];
    const float x2 = xb[(size_t)(c4*4+2)*TF_];
    const float x3 = xb[(size_t)(c4*4+3)*TF_];
    #pragma unroll
    for (int o=0;o<16;o++){
      float4 w = w4[o*16+c4];
      accq[o] = fmaf(w.w,x3,fmaf(w.z,x2,fmaf(w.y,x1,fmaf(w.x,x0,accq[o]))));
    }
    #pragma unroll
    for (int o=0;o<16;o++){
      float4 w = w4[256+o*16+c4];
      acck[o] = fmaf(w.w,x3,fmaf(w.z,x2,fmaf(w.y,x1,fmaf(w.x,x0,acck[o]))));
    }
    #pragma unroll
    for (int o=0;o<64;o++){
      float4 w = w4[512+o*16+c4];
      accv[o] = fmaf(w.w,x3,fmaf(w.z,x2,fmaf(w.y,x1,fmaf(w.x,x0,accv[o]))));
    }
  }

  #pragma unroll
  for (int h=0; h<H_; h++){
    const int bh = b*H_ + h;
    { // Q: bias, PReLU, LN over D=4
      float v[4]; float s = 0.f;
      #pragma unroll
      for (int d=0; d<4; d++){
        float a = accq[h*4+d] + prm[h*4+d];
        a = (a >= 0.f) ? a : prm[16+h]*a;
        v[d] = a; s += a;
      }
      float mu = s * 0.25f;
      float var = 0.f;
      #pragma unroll
      for (int d=0; d<4; d++){ float dd = v[d]-mu; var = fmaf(dd,dd,var); }
      var *= 0.25f;
      float rs = rsqrtf(var + 1e-5f);
      u16* qrow = Qf + ((size_t)bh*TP + t)*SQK + f;
      #pragma unroll
      for (int d=0; d<4; d++)
        qrow[d*F_] = f2bf((v[d]-mu)*rs*prm[20+h*4+d] + prm[36+h*4+d]);
    }
    { // K
      float v[4]; float s = 0.f;
      #pragma unroll
      for (int d=0; d<4; d++){
        float a = acck[h*4+d] + prm[52+h*4+d];
        a = (a >= 0.f) ? a : prm[68+h]*a;
        v[d] = a; s += a;
      }
      float mu = s * 0.25f;
      float var = 0.f;
      #pragma unroll
      for (int d=0; d<4; d++){ float dd = v[d]-mu; var = fmaf(dd,dd,var); }
      var *= 0.25f;
      float rs = rsqrtf(var + 1e-5f);
      u16* krow = Kf + ((size_t)bh*TP + t)*SQK + f;
      #pragma unroll
      for (int d=0; d<4; d++)
        krow[d*F_] = f2bf((v[d]-mu)*rs*prm[72+h*4+d] + prm[88+h*4+d]);
    }
    { // V: LN over E=16
      float v[16]; float s = 0.f;
      #pragma unroll
      for (int e=0; e<16; e++){
        float a = accv[h*16+e] + prm[104+h*16+e];
        a = (a >= 0.f) ? a : prm[168+h]*a;
        v[e] = a; s += a;
      }
      float mu = s * (1.f/16.f);
      float var = 0.f;
      #pragma unroll
      for (int e=0; e<16; e++){ float dd = v[e]-mu; var = fmaf(dd,dd,var); }
      var *= (1.f/16.f);
      float rs = rsqrtf(var + 1e-5f);
      u16* vrow = Vf + ((size_t)bh*T_ + t)*EF + f;
      #pragma unroll
      for (int e=0; e<16; e++)
        vrow[e*F_] = f2bf((v[e]-mu)*rs*prm[172+h*16+e] + prm[236+h*16+e]);
    }
  }
}

// ---------------------------------------------------------------------------
// K2: transpose V -> Vt [8][1152][3008] bf16 (keys>=3000 and cols>=1040 -> 0)
// ---------------------------------------------------------------------------
__global__ __launch_bounds__(256) void vtrans_kernel(
    const u16* __restrict__ Vf, u16* __restrict__ Vt)
{
  __shared__ u16 tile[64][68];
  const int bh = blockIdx.z, t0 = blockIdx.x*64, c0 = blockIdx.y*64;
  const int tid = threadIdx.x;
  const int rr = tid>>4, cc4 = (tid&15)*4;
  #pragma unroll
  for (int i=0;i<4;i++){
    const int key = t0 + rr + i*16;
    ushort4 v = {0,0,0,0};
    if (key < T_) {
      const u16* src = Vf + ((size_t)bh*T_ + key)*EF + c0 + cc4;
      if (c0 + cc4 + 3 < EF) v = *(const ushort4*)src;
      else {
        if (c0+cc4+0 < EF) v.x = src[0];
        if (c0+cc4+1 < EF) v.y = src[1];
        if (c0+cc4+2 < EF) v.z = src[2];
        if (c0+cc4+3 < EF) v.w = src[3];
      }
    }
    *(ushort4*)&tile[rr + i*16][cc4] = v;
  }
  __syncthreads();
  #pragma unroll
  for (int i=0;i<4;i++){
    const int cl = rr + i*16;
    const int col = c0 + cl;
    ushort4 v;
    v.x = tile[cc4+0][cl];
    v.y = tile[cc4+1][cl];
    v.z = tile[cc4+2][cl];
    v.w = tile[cc4+3][cl];
    *(ushort4*)(Vt + ((size_t)bh*VTROWS + col)*TK + t0 + cc4) = v;
  }
}

// ---------------------------------------------------------------------------
// shared GEMM core: C(128x128) += A(128xK) * B(128xK)^T, bf16, m97-style.
// A,B row-major with 8-elem chunks XOR-swizzled into LDS via global_load_lds.
// wave w covers rows (w&1)*64.., cols (w>>1)*64.., 4x4 tiles of 16x16x32.
// ---------------------------------------------------------------------------
__device__ __forceinline__ void gemm_core(
    const u16* __restrict__ Ag, const u16* __restrict__ Bg,
    size_t strideA, size_t strideB, int niter,
    u16* As, u16* Bs, f32x4 acc[4][4], int w, int l)
{
  const int c0l = w*128 + l;
  const int c1l = c0l + 64;
  const int r0s = c0l>>2, jg0 = (c0l&3) ^ ((r0s>>1)&3);
  const int r1s = c1l>>2, jg1 = (c1l&3) ^ ((r1s>>1)&3);
  u16* lA0 = As + (size_t)(w*128)*8;
  u16* lA1 = As + (size_t)(w*128+64)*8;
  u16* lB0 = Bs + (size_t)(w*128)*8;
  u16* lB1 = Bs + (size_t)(w*128+64)*8;
  const int m = l & 15, q = l >> 4;
  const int sw = (q ^ ((m>>1)&3)) << 3;     // swizzled chunk slot offset (elems)
  const int ra = (w&1)*64 + m;
  const int rb = (w>>1)*64 + m;

  for (int it = 0; it < niter; ++it) {
    const int k0 = it*32;
    __syncthreads();
    gld16(Ag + (size_t)r0s*strideA + k0 + jg0*8, lA0);
    gld16(Ag + (size_t)r1s*strideA + k0 + jg1*8, lA1);
    gld16(Bg + (size_t)r0s*strideB + k0 + jg0*8, lB0);
    gld16(Bg + (size_t)r1s*strideB + k0 + jg1*8, lB1);
    __syncthreads();
    s16x8 a[4], b[4];
    #pragma unroll
    for (int i=0;i<4;i++) a[i] = *(const s16x8*)(As + (ra + i*16)*32 + sw);
    #pragma unroll
    for (int j=0;j<4;j++) b[j] = *(const s16x8*)(Bs + (rb + j*16)*32 + sw);
    #pragma unroll
    for (int i=0;i<4;i++)
      #pragma unroll
      for (int j=0;j<4;j++)
        acc[i][j] = __builtin_amdgcn_mfma_f32_16x16x32_bf16(a[i], b[j], acc[i][j], 0, 0, 0);
  }
}

// ---------------------------------------------------------------------------
// K3: scores -> P~ = exp(scale * Q K^T) bf16 [z][3072][3072], l row-sums (atomic)
// ---------------------------------------------------------------------------
__global__ __launch_bounds__(256) void scores_kernel(
    const u16* __restrict__ Qf, const u16* __restrict__ Kf,
    u16* __restrict__ P, float* __restrict__ lbuf, int chunk)
{
  __shared__ __align__(16) u16 As[128*32];
  __shared__ __align__(16) u16 Bs[128*32];
  const int tid = threadIdx.x, w = tid>>6, l = tid&63;
  const int bh = chunk*2 + blockIdx.z;
  const int row0 = blockIdx.x*128, col0 = blockIdx.y*128;
  const u16* Ag = Qf + ((size_t)bh*TP + row0)*SQK;
  const u16* Bg = Kf + ((size_t)bh*TP + col0)*SQK;

  f32x4 acc[4][4];
  #pragma unroll
  for (int i=0;i<4;i++)
    #pragma unroll
    for (int j=0;j<4;j++) acc[i][j] = (f32x4){0.f,0.f,0.f,0.f};

  gemm_core(Ag, Bg, SQK, SQK, 9, As, Bs, acc, w, l);

  const float scale = 0.062017367294604234f;   // 1/sqrt(260)
  const int m = l & 15, q = l >> 4;
  u16* Pz = P + (size_t)blockIdx.z*TP*TP;
  float* lrow = lbuf + (size_t)bh*TP;

  #pragma unroll
  for (int i=0;i<4;i++){
    #pragma unroll
    for (int reg=0; reg<4; reg++){
      const int grow = row0 + (w&1)*64 + i*16 + q*4 + reg;
      float rsum = 0.f;
      #pragma unroll
      for (int j=0;j<4;j++){
        const int gcol = col0 + (w>>1)*64 + j*16 + m;
        float pv = __expf(acc[i][j][reg]*scale);
        if (gcol >= T_) pv = 0.f;
        rsum += pv;
        Pz[(size_t)grow*TP + gcol] = f2bf(pv);
      }
      rsum += __shfl_xor(rsum, 8);
      rsum += __shfl_xor(rsum, 4);
      rsum += __shfl_xor(rsum, 2);
      rsum += __shfl_xor(rsum, 1);
      if (m == 0) atomicAdd(&lrow[grow], rsum);
    }
  }
}

// ---------------------------------------------------------------------------
// K4: O = (P~ * V) / l  -> bf16 [8][3000][1040]
// ---------------------------------------------------------------------------
__global__ __launch_bounds__(256) void pv_kernel(
    const u16* __restrict__ P, const u16* __restrict__ Vt,
    const float* __restrict__ lbuf, u16* __restrict__ Oo, int chunk)
{
  __shared__ __align__(16) u16 As[128*32];
  __shared__ __align__(16) u16 Bs[128*32];
  const int tid = threadIdx.x, w = tid>>6, l = tid&63;
  const int bh = chunk*2 + blockIdx.z;
  const int row0 = blockIdx.x*128, col0 = blockIdx.y*128;
  const u16* Ag = P + (size_t)blockIdx.z*TP*TP + (size_t)row0*TP;
  const u16* Bg = Vt + ((size_t)bh*VTROWS + col0)*TK;

  f32x4 acc[4][4];
  #pragma unroll
  for (int i=0;i<4;i++)
    #pragma unroll
    for (int j=0;j<4;j++) acc[i][j] = (f32x4){0.f,0.f,0.f,0.f};

  gemm_core(Ag, Bg, TP, TK, 94, As, Bs, acc, w, l);

  const int m = l & 15, q = l >> 4;
  const float* lrow = lbuf + (size_t)bh*TP;

  #pragma unroll
  for (int i=0;i<4;i++){
    #pragma unroll
    for (int reg=0; reg<4; reg++){
      const int grow = row0 + (w&1)*64 + i*16 + q*4 + reg;
      if (grow >= T_) continue;
      const float linv = 1.0f / lrow[grow];
      u16* orow = Oo + ((size_t)bh*T_ + grow)*EF;
      #pragma unroll
      for (int j=0;j<4;j++){
        const int gcol = col0 + (w>>1)*64 + j*16 + m;
        if (gcol < EF) orow[gcol] = f2bf(acc[i][j][reg]*linv);
      }
    }
  }
}

// ---------------------------------------------------------------------------
// K5: final 1x1 conv (64x64) + PReLU + LN over C + residual
// ---------------------------------------------------------------------------
__global__ __launch_bounds__(256) void outp_kernel(
    const u16* __restrict__ Oo, const float* __restrict__ x,
    const float* __restrict__ Wp, const float* __restrict__ bp, const float* __restrict__ ap,
    const float* __restrict__ gp, const float* __restrict__ btep,
    float* __restrict__ out)
{
  __shared__ __align__(16) float4 wp4[1024];
  __shared__ float prm[193];
  const int tid = threadIdx.x;
  {
    const float4* wp = (const float4*)Wp;
    for (int i = tid; i < 1024; i += 256) wp4[i] = wp[i];
    if (tid < 193) {
      float v;
      if      (tid < 64)  v = bp[tid];
      else if (tid < 128) v = gp[tid-64];
      else if (tid < 192) v = btep[tid-128];
      else                v = ap[0];
      prm[tid] = v;
    }
  }
  __syncthreads();
  const int p = blockIdx.x*256 + tid;
  if (p >= NPT) return;
  const int b = p / TF_;
  const int r = p - b*TF_;
  const int t = r / F_;
  const int f = r - t*F_;

  float4 ov[16];   // 64 attention-output channels, c = h*16 + e
  #pragma unroll
  for (int h=0; h<4; h++){
    const u16* ob = Oo + ((size_t)(b*H_+h)*T_ + t)*EF + f;
    #pragma unroll
    for (int e4=0; e4<4; e4++){
      float4 vv;
      vv.x = bf2f(ob[(e4*4+0)*F_]);
      vv.y = bf2f(ob[(e4*4+1)*F_]);
      vv.z = bf2f(ob[(e4*4+2)*F_]);
      vv.w = bf2f(ob[(e4*4+3)*F_]);
      ov[h*4+e4] = vv;
    }
  }
  const float apv = prm[192];
  float y[64];
  float ssum = 0.f, ssq = 0.f;
  #pragma unroll
  for (int o=0; o<64; o++){
    float a = prm[o];
    #pragma unroll
    for (int c4=0; c4<16; c4++){
      float4 wv = wp4[o*16+c4];
      float4 xv = ov[c4];
      a = fmaf(wv.w,xv.w,fmaf(wv.z,xv.z,fmaf(wv.y,xv.y,fmaf(wv.x,xv.x,a))));
    }
    a = (a >= 0.f) ? a : apv*a;
    y[o] = a; ssum += a; ssq = fmaf(a,a,ssq);
  }
  const float mu = ssum * (1.f/64.f);
  const float var = ssq * (1.f/64.f) - mu*mu;
  const float rs = rsqrtf(var + 1e-5f);
  const float* xb = x + (size_t)b*C_*TF_ + r;
  float* yb = out + (size_t)b*C_*TF_ + r;
  #pragma unroll
  for (int o=0; o<64; o++){
    yb[(size_t)o*TF_] = fmaf((y[o]-mu)*rs, prm[64+o], prm[128+o]) + xb[(size_t)o*TF_];
  }
}

// ---------------------------------------------------------------------------
extern "C" void kernel_launch(void* const* d_in, const int* in_sizes, int n_in,
                              void* d_out, int out_size, void* d_ws, size_t ws_size,
                              hipStream_t stream)
{
  const float* x    = (const float*)d_in[0];
  const float* Wq   = (const float*)d_in[1];
  const float* bq   = (const float*)d_in[2];
  const float* aq   = (const float*)d_in[3];
  const float* gq   = (const float*)d_in[4];
  const float* bteq = (const float*)d_in[5];
  const float* Wk   = (const float*)d_in[6];
  const float* bk   = (const float*)d_in[7];
  const float* ak   = (const float*)d_in[8];
  const float* gk   = (const float*)d_in[9];
  const float* btek = (const float*)d_in[10];
  const float* Wv   = (const float*)d_in[11];
  const float* bv   = (const float*)d_in[12];
  const float* av   = (const float*)d_in[13];
  const float* gv   = (const float*)d_in[14];
  const float* btev = (const float*)d_in[15];
  const float* Wp   = (const float*)d_in[16];
  const float* bp   = (const float*)d_in[17];
  const float* ap   = (const float*)d_in[18];
  const float* gp   = (const float*)d_in[19];
  const float* btep = (const float*)d_in[20];

  // workspace layout (bytes):
  //   Qf   bf16 [8][3072][328]   @ 0            (16,121,856)
  //   Kf   bf16 [8][3072][328]   @ 16,121,856   (16,121,856)
  //   Vf   bf16 [8][3000][1040]  @ 32,243,712   (49,920,000)  -- dead after vtrans
  //   Oo   bf16 [8][3000][1040]  @ 32,243,712   (49,920,000)  -- overlays Vf
  //   Vt   bf16 [8][1152][3008]  @ 82,163,712   (55,443,456)
  //   P    bf16 [2][3072][3072]  @ 137,607,168  (37,748,736)  -- bh-pair chunks
  //   lbuf f32  [8][3072]        @ 175,355,904  (98,304)      -> total 175,454,208
  char* ws = (char*)d_ws;
  u16*   Qf   = (u16*)(ws + 0);
  u16*   Kf   = (u16*)(ws + 16121856);
  u16*   Vf   = (u16*)(ws + 32243712);
  u16*   Oo   = (u16*)(ws + 32243712);
  u16*   Vt   = (u16*)(ws + 82163712);
  u16*   P    = (u16*)(ws + 137607168);
  float* lbuf = (float*)(ws + 175355904);
  float* out  = (float*)d_out;

  qkv_kernel<<<dim3((NPT+255)/256), dim3(256), 0, stream>>>(
      x, Wq,bq,aq,gq,bteq, Wk,bk,ak,gk,btek, Wv,bv,av,gv,btev, Qf,Kf,Vf, lbuf);
  vtrans_kernel<<<dim3(47, 17, 8), dim3(256), 0, stream>>>(Vf, Vt);
  for (int c = 0; c < 4; ++c) {
    scores_kernel<<<dim3(24, 24, 2), dim3(256), 0, stream>>>(Qf, Kf, P, lbuf, c);
    pv_kernel<<<dim3(24, 9, 2), dim3(256), 0, stream>>>(P, Vt, lbuf, Oo, c);
  }
  outp_kernel<<<dim3((NPT+255)/256), dim3(256), 0, stream>>>(
      Oo, x, Wp,bp,ap,gp,btep, out);
}

// Round 3
// 952.875 us; speedup vs baseline: 6.2115x; 1.0550x over previous
//
#include <hip/hip_runtime.h>
#include <stdint.h>

#define B_ 2
#define C_ 64
#define T_ 3000
#define F_ 65
#define H_ 4
#define D_ 4
#define E_ 16
#define TF_ (T_*F_)          // 195000
#define NPT (B_*TF_)         // 390000
#define EF 1040              // E*F
#define TP 3072              // padded T for GEMM row/col blocks (24*128)
#define TK 3008              // padded key dim for Vt (47*64)
#define DQK 260              // D*F (live Q/K cols)
#define SQK 328              // Q/K global row stride
#define VTROWS 1152          // padded V cols (9*128)

typedef unsigned short u16;
typedef unsigned int   u32;
typedef __attribute__((ext_vector_type(8))) short  s16x8;
typedef __attribute__((ext_vector_type(4))) float  f32x4;

__device__ __forceinline__ float bf2f(u16 u){ return __uint_as_float(((u32)u)<<16); }
__device__ __forceinline__ float bf2f_lo(u32 u){ return __uint_as_float(u<<16); }
__device__ __forceinline__ float bf2f_hi(u32 u){ return __uint_as_float(u & 0xffff0000u); }
__device__ __forceinline__ u16 f2bf(float f){
  u32 u = __float_as_uint(f);
  u32 r = u + 0x7fffu + ((u>>16)&1u);   // RNE
  return (u16)(r>>16);
}

__device__ __forceinline__ void gld16(const u16* g, u16* l){
  __builtin_amdgcn_global_load_lds((const __attribute__((address_space(1))) u32*)g,
                                   (__attribute__((address_space(3))) u32*)l,
                                   16, 0, 0);
}

// ---------------------------------------------------------------------------
// K1: per-head 1x1 conv Q/K/V + PReLU + channel-LN
//  -> Qf/Kf bf16 [8][3072][328], Vf bf16 [8][3000][1040]; zeroes lbuf
// ---------------------------------------------------------------------------
__global__ __launch_bounds__(256) void qkv_kernel(
    const float* __restrict__ x,
    const float* __restrict__ Wq, const float* __restrict__ bq, const float* __restrict__ aq,
    const float* __restrict__ gq, const float* __restrict__ bteq,
    const float* __restrict__ Wk, const float* __restrict__ bk, const float* __restrict__ ak,
    const float* __restrict__ gk, const float* __restrict__ btek,
    const float* __restrict__ Wv, const float* __restrict__ bv, const float* __restrict__ av,
    const float* __restrict__ gv, const float* __restrict__ btev,
    u16* __restrict__ Qf, u16* __restrict__ Kf, u16* __restrict__ Vf,
    float* __restrict__ lbuf)
{
  __shared__ __align__(16) float4 w4[1536];   // Wq(256) Wk(256) Wv(1024) as float4
  __shared__ float prm[304];
  const int tid = threadIdx.x;
  {
    const float4* a = (const float4*)Wq;
    const float4* b = (const float4*)Wk;
    const float4* c = (const float4*)Wv;
    for (int i = tid; i < 1536; i += 256)
      w4[i] = (i < 256) ? a[i] : (i < 512) ? b[i-256] : c[i-512];
    for (int i = tid; i < 304; i += 256) {
      float v = 0.f;
      if      (i < 16)  v = bq[i];
      else if (i < 20)  v = aq[i-16];
      else if (i < 36)  v = gq[i-20];
      else if (i < 52)  v = bteq[i-36];
      else if (i < 68)  v = bk[i-52];
      else if (i < 72)  v = ak[i-68];
      else if (i < 88)  v = gk[i-72];
      else if (i < 104) v = btek[i-88];
      else if (i < 168) v = bv[i-104];
      else if (i < 172) v = av[i-168];
      else if (i < 236) v = gv[i-172];
      else if (i < 300) v = btev[i-236];
      prm[i] = v;
    }
  }
  const int p = blockIdx.x*256 + tid;
  if (p < 8*TP) lbuf[p] = 0.f;   // zero the softmax-denominator accumulator
  __syncthreads();
  if (p >= NPT) return;
  const int b = p / TF_;
  const int r = p - b*TF_;
  const int t = r / F_;
  const int f = r - t*F_;
  const float* xb = x + (size_t)b*C_*TF_ + r;

  float accq[16], acck[16], accv[64];
  #pragma unroll
  for (int i=0;i<16;i++){ accq[i]=0.f; acck[i]=0.f; }
  #pragma unroll
  for (int i=0;i<64;i++) accv[i]=0.f;

  for (int c4 = 0; c4 < 16; ++c4) {
    const float x0 = xb[(size_t)(c4*4+0)*TF_];
    const float x1 = xb[(size_t)(c4*4+1)*TF_];
    const float x2 = xb[(size_t)(c4*4+2)*TF_];
    const float x3 = xb[(size_t)(c4*4+3)*TF_];
    #pragma unroll
    for (int o=0;o<16;o++){
      float4 w = w4[o*16+c4];
      accq[o] = fmaf(w.w,x3,fmaf(w.z,x2,fmaf(w.y,x1,fmaf(w.x,x0,accq[o]))));
    }
    #pragma unroll
    for (int o=0;o<16;o++){
      float4 w = w4[256+o*16+c4];
      acck[o] = fmaf(w.w,x3,fmaf(w.z,x2,fmaf(w.y,x1,fmaf(w.x,x0,acck[o]))));
    }
    #pragma unroll
    for (int o=0;o<64;o++){
      float4 w = w4[512+o*16+c4];
      accv[o] = fmaf(w.w,x3,fmaf(w.z,x2,fmaf(w.y,x1,fmaf(w.x,x0,accv[o]))));
    }
  }

  #pragma unroll
  for (int h=0; h<H_; h++){
    const int bh = b*H_ + h;
    { // Q: bias, PReLU, LN over D=4
      float v[4]; float s = 0.f;
      #pragma unroll
      for (int d=0; d<4; d++){
        float a = accq[h*4+d] + prm[h*4+d];
        a = (a >= 0.f) ? a : prm[16+h]*a;
        v[d] = a; s += a;
      }
      float mu = s * 0.25f;
      float var = 0.f;
      #pragma unroll
      for (int d=0; d<4; d++){ float dd = v[d]-mu; var = fmaf(dd,dd,var); }
      var *= 0.25f;
      float rs = rsqrtf(var + 1e-5f);
      u16* qrow = Qf + ((size_t)bh*TP + t)*SQK + f;
      #pragma unroll
      for (int d=0; d<4; d++)
        qrow[d*F_] = f2bf((v[d]-mu)*rs*prm[20+h*4+d] + prm[36+h*4+d]);
    }
    { // K
      float v[4]; float s = 0.f;
      #pragma unroll
      for (int d=0; d<4; d++){
        float a = acck[h*4+d] + prm[52+h*4+d];
        a = (a >= 0.f) ? a : prm[68+h]*a;
        v[d] = a; s += a;
      }
      float mu = s * 0.25f;
      float var = 0.f;
      #pragma unroll
      for (int d=0; d<4; d++){ float dd = v[d]-mu; var = fmaf(dd,dd,var); }
      var *= 0.25f;
      float rs = rsqrtf(var + 1e-5f);
      u16* krow = Kf + ((size_t)bh*TP + t)*SQK + f;
      #pragma unroll
      for (int d=0; d<4; d++)
        krow[d*F_] = f2bf((v[d]-mu)*rs*prm[72+h*4+d] + prm[88+h*4+d]);
    }
    { // V: LN over E=16
      float v[16]; float s = 0.f;
      #pragma unroll
      for (int e=0; e<16; e++){
        float a = accv[h*16+e] + prm[104+h*16+e];
        a = (a >= 0.f) ? a : prm[168+h]*a;
        v[e] = a; s += a;
      }
      float mu = s * (1.f/16.f);
      float var = 0.f;
      #pragma unroll
      for (int e=0; e<16; e++){ float dd = v[e]-mu; var = fmaf(dd,dd,var); }
      var *= (1.f/16.f);
      float rs = rsqrtf(var + 1e-5f);
      u16* vrow = Vf + ((size_t)bh*T_ + t)*EF + f;
      #pragma unroll
      for (int e=0; e<16; e++)
        vrow[e*F_] = f2bf((v[e]-mu)*rs*prm[172+h*16+e] + prm[236+h*16+e]);
    }
  }
}

// ---------------------------------------------------------------------------
// K2: transpose V -> Vt [8][1152][3008] bf16 (keys>=3000 and cols>=1040 -> 0)
// ---------------------------------------------------------------------------
__global__ __launch_bounds__(256) void vtrans_kernel(
    const u16* __restrict__ Vf, u16* __restrict__ Vt)
{
  __shared__ u16 tile[64][68];
  const int bh = blockIdx.z, t0 = blockIdx.x*64, c0 = blockIdx.y*64;
  const int tid = threadIdx.x;
  const int rr = tid>>4, cc4 = (tid&15)*4;
  #pragma unroll
  for (int i=0;i<4;i++){
    const int key = t0 + rr + i*16;
    ushort4 v = {0,0,0,0};
    if (key < T_) {
      const u16* src = Vf + ((size_t)bh*T_ + key)*EF + c0 + cc4;
      if (c0 + cc4 + 3 < EF) v = *(const ushort4*)src;
      else {
        if (c0+cc4+0 < EF) v.x = src[0];
        if (c0+cc4+1 < EF) v.y = src[1];
        if (c0+cc4+2 < EF) v.z = src[2];
        if (c0+cc4+3 < EF) v.w = src[3];
      }
    }
    *(ushort4*)&tile[rr + i*16][cc4] = v;
  }
  __syncthreads();
  #pragma unroll
  for (int i=0;i<4;i++){
    const int cl = rr + i*16;
    const int col = c0 + cl;
    ushort4 v;
    v.x = tile[cc4+0][cl];
    v.y = tile[cc4+1][cl];
    v.z = tile[cc4+2][cl];
    v.w = tile[cc4+3][cl];
    *(ushort4*)(Vt + ((size_t)bh*VTROWS + col)*TK + t0 + cc4) = v;
  }
}

// ---------------------------------------------------------------------------
// shared GEMM core: C(128x128) += A(128xK) * B(128xK)^T, bf16, m97-style.
// ---------------------------------------------------------------------------
__device__ __forceinline__ void gemm_core(
    const u16* __restrict__ Ag, const u16* __restrict__ Bg,
    size_t strideA, size_t strideB, int niter,
    u16* As, u16* Bs, f32x4 acc[4][4], int w, int l)
{
  const int c0l = w*128 + l;
  const int c1l = c0l + 64;
  const int r0s = c0l>>2, jg0 = (c0l&3) ^ ((r0s>>1)&3);
  const int r1s = c1l>>2, jg1 = (c1l&3) ^ ((r1s>>1)&3);
  u16* lA0 = As + (size_t)(w*128)*8;
  u16* lA1 = As + (size_t)(w*128+64)*8;
  u16* lB0 = Bs + (size_t)(w*128)*8;
  u16* lB1 = Bs + (size_t)(w*128+64)*8;
  const int m = l & 15, q = l >> 4;
  const int sw = (q ^ ((m>>1)&3)) << 3;     // swizzled chunk slot offset (elems)
  const int ra = (w&1)*64 + m;
  const int rb = (w>>1)*64 + m;

  for (int it = 0; it < niter; ++it) {
    const int k0 = it*32;
    __syncthreads();
    gld16(Ag + (size_t)r0s*strideA + k0 + jg0*8, lA0);
    gld16(Ag + (size_t)r1s*strideA + k0 + jg1*8, lA1);
    gld16(Bg + (size_t)r0s*strideB + k0 + jg0*8, lB0);
    gld16(Bg + (size_t)r1s*strideB + k0 + jg1*8, lB1);
    __syncthreads();
    s16x8 a[4], b[4];
    #pragma unroll
    for (int i=0;i<4;i++) a[i] = *(const s16x8*)(As + (ra + i*16)*32 + sw);
    #pragma unroll
    for (int j=0;j<4;j++) b[j] = *(const s16x8*)(Bs + (rb + j*16)*32 + sw);
    #pragma unroll
    for (int i=0;i<4;i++)
      #pragma unroll
      for (int j=0;j<4;j++)
        acc[i][j] = __builtin_amdgcn_mfma_f32_16x16x32_bf16(a[i], b[j], acc[i][j], 0, 0, 0);
  }
}

// ---------------------------------------------------------------------------
// K3: scores -> P~ = exp(scale * Q K^T) bf16 [z][3072][3072], l row-sums (atomic)
// ---------------------------------------------------------------------------
__global__ __launch_bounds__(256) void scores_kernel(
    const u16* __restrict__ Qf, const u16* __restrict__ Kf,
    u16* __restrict__ P, float* __restrict__ lbuf, int chunk)
{
  __shared__ __align__(16) u16 As[128*32];
  __shared__ __align__(16) u16 Bs[128*32];
  const int tid = threadIdx.x, w = tid>>6, l = tid&63;
  const int bh = chunk*2 + blockIdx.z;
  const int row0 = blockIdx.x*128, col0 = blockIdx.y*128;
  const u16* Ag = Qf + ((size_t)bh*TP + row0)*SQK;
  const u16* Bg = Kf + ((size_t)bh*TP + col0)*SQK;

  f32x4 acc[4][4];
  #pragma unroll
  for (int i=0;i<4;i++)
    #pragma unroll
    for (int j=0;j<4;j++) acc[i][j] = (f32x4){0.f,0.f,0.f,0.f};

  gemm_core(Ag, Bg, SQK, SQK, 9, As, Bs, acc, w, l);

  const float scale = 0.062017367294604234f;   // 1/sqrt(260)
  const int m = l & 15, q = l >> 4;
  u16* Pz = P + (size_t)blockIdx.z*TP*TP;
  float* lrow = lbuf + (size_t)bh*TP;

  #pragma unroll
  for (int i=0;i<4;i++){
    #pragma unroll
    for (int reg=0; reg<4; reg++){
      const int grow = row0 + (w&1)*64 + i*16 + q*4 + reg;
      float rsum = 0.f;
      #pragma unroll
      for (int j=0;j<4;j++){
        const int gcol = col0 + (w>>1)*64 + j*16 + m;
        float pv = __expf(acc[i][j][reg]*scale);
        if (gcol >= T_) pv = 0.f;
        rsum += pv;
        Pz[(size_t)grow*TP + gcol] = f2bf(pv);
      }
      rsum += __shfl_xor(rsum, 8);
      rsum += __shfl_xor(rsum, 4);
      rsum += __shfl_xor(rsum, 2);
      rsum += __shfl_xor(rsum, 1);
      if (m == 0) atomicAdd(&lrow[grow], rsum);
    }
  }
}

// ---------------------------------------------------------------------------
// K4: O = (P~ * V) / l  -> Opt bf16 [b][t*65+f][64]  (channel-contiguous)
// ---------------------------------------------------------------------------
__global__ __launch_bounds__(256) void pv_kernel(
    const u16* __restrict__ P, const u16* __restrict__ Vt,
    const float* __restrict__ lbuf, u16* __restrict__ Opt, int chunk)
{
  __shared__ __align__(16) u16 As[128*32];
  __shared__ __align__(16) u16 Bs[128*32];
  const int tid = threadIdx.x, w = tid>>6, l = tid&63;
  const int bh = chunk*2 + blockIdx.z;
  const int row0 = blockIdx.x*128, col0 = blockIdx.y*128;
  const u16* Ag = P + (size_t)blockIdx.z*TP*TP + (size_t)row0*TP;
  const u16* Bg = Vt + ((size_t)bh*VTROWS + col0)*TK;

  f32x4 acc[4][4];
  #pragma unroll
  for (int i=0;i<4;i++)
    #pragma unroll
    for (int j=0;j<4;j++) acc[i][j] = (f32x4){0.f,0.f,0.f,0.f};

  gemm_core(Ag, Bg, TP, TK, 94, As, Bs, acc, w, l);

  const int m = l & 15, q = l >> 4;
  const float* lrow = lbuf + (size_t)bh*TP;
  const int b = bh >> 2, h = bh & 3;
  u16* Ob = Opt + (size_t)b*TF_*64 + h*16;   // + (t*65+f)*64 + e

  #pragma unroll
  for (int i=0;i<4;i++){
    #pragma unroll
    for (int reg=0; reg<4; reg++){
      const int grow = row0 + (w&1)*64 + i*16 + q*4 + reg;
      if (grow >= T_) continue;
      const float linv = 1.0f / lrow[grow];
      #pragma unroll
      for (int j=0;j<4;j++){
        const int gcol = col0 + (w>>1)*64 + j*16 + m;
        if (gcol < EF) {
          const int e = (gcol*1009) >> 16;       // gcol/65 for gcol<1040
          const int f = gcol - e*65;
          Ob[((size_t)grow*65 + f)*64 + e] = f2bf(acc[i][j][reg]*linv);
        }
      }
    }
  }
}

// ---------------------------------------------------------------------------
// K5: final 1x1 conv (64x64) + PReLU + LN over C + residual
// Opt channel-contiguous: per point, 64 bf16 read as 8x uint4 (128 B).
// y computed once, packed to bf16 pairs for the store pass (no recompute).
// ---------------------------------------------------------------------------
__global__ __launch_bounds__(256) void outp_kernel(
    const u16* __restrict__ Opt, const float* __restrict__ x,
    const float* __restrict__ Wp, const float* __restrict__ bp, const float* __restrict__ ap,
    const float* __restrict__ gp, const float* __restrict__ btep,
    float* __restrict__ out)
{
  __shared__ __align__(16) float4 wp4[1024];
  __shared__ float prm[193];
  const int tid = threadIdx.x;
  {
    const float4* wp = (const float4*)Wp;
    for (int i = tid; i < 1024; i += 256) wp4[i] = wp[i];
    if (tid < 193) {
      float v;
      if      (tid < 64)  v = bp[tid];
      else if (tid < 128) v = gp[tid-64];
      else if (tid < 192) v = btep[tid-128];
      else                v = ap[0];
      prm[tid] = v;
    }
  }
  __syncthreads();
  const int p = blockIdx.x*256 + tid;
  if (p >= NPT) return;
  const int b = p / TF_;
  const int r = p - b*TF_;

  // load 64 contiguous bf16 channels for this point
  float4 ov[16];
  {
    const uint4* op = (const uint4*)(Opt + (size_t)p*64);
    #pragma unroll
    for (int i=0;i<8;i++){
      uint4 v = op[i];
      ov[i*2+0] = (float4){bf2f_lo(v.x), bf2f_hi(v.x), bf2f_lo(v.y), bf2f_hi(v.y)};
      ov[i*2+1] = (float4){bf2f_lo(v.z), bf2f_hi(v.z), bf2f_lo(v.w), bf2f_hi(v.w)};
    }
  }
  const float apv = prm[192];
  float ssum = 0.f, ssq = 0.f;
  u32 ypk[32];
  #pragma unroll
  for (int o2=0; o2<32; o2++){
    float a0 = prm[o2*2], a1 = prm[o2*2+1];
    #pragma unroll
    for (int c4=0; c4<16; c4++){
      float4 xv = ov[c4];
      float4 w0 = wp4[(o2*2)*16+c4];
      float4 w1 = wp4[(o2*2+1)*16+c4];
      a0 = fmaf(w0.w,xv.w,fmaf(w0.z,xv.z,fmaf(w0.y,xv.y,fmaf(w0.x,xv.x,a0))));
      a1 = fmaf(w1.w,xv.w,fmaf(w1.z,xv.z,fmaf(w1.y,xv.y,fmaf(w1.x,xv.x,a1))));
    }
    a0 = (a0 >= 0.f) ? a0 : apv*a0;
    a1 = (a1 >= 0.f) ? a1 : apv*a1;
    ssum += a0 + a1;
    ssq = fmaf(a0,a0,fmaf(a1,a1,ssq));
    ypk[o2] = (u32)f2bf(a0) | ((u32)f2bf(a1) << 16);
  }
  const float mu = ssum * (1.f/64.f);
  const float var = ssq * (1.f/64.f) - mu*mu;
  const float rs = rsqrtf(var + 1e-5f);
  const float* xb = x + (size_t)b*C_*TF_ + r;
  float* yb = out + (size_t)b*C_*TF_ + r;
  #pragma unroll
  for (int o2=0; o2<32; o2++){
    const u32 v = ypk[o2];
    const float y0 = bf2f_lo(v), y1 = bf2f_hi(v);
    const int o = o2*2;
    yb[(size_t)o*TF_]     = fmaf((y0-mu)*rs, prm[64+o],   prm[128+o])   + xb[(size_t)o*TF_];
    yb[(size_t)(o+1)*TF_] = fmaf((y1-mu)*rs, prm[64+o+1], prm[128+o+1]) + xb[(size_t)(o+1)*TF_];
  }
}

// ---------------------------------------------------------------------------
extern "C" void kernel_launch(void* const* d_in, const int* in_sizes, int n_in,
                              void* d_out, int out_size, void* d_ws, size_t ws_size,
                              hipStream_t stream)
{
  const float* x    = (const float*)d_in[0];
  const float* Wq   = (const float*)d_in[1];
  const float* bq   = (const float*)d_in[2];
  const float* aq   = (const float*)d_in[3];
  const float* gq   = (const float*)d_in[4];
  const float* bteq = (const float*)d_in[5];
  const float* Wk   = (const float*)d_in[6];
  const float* bk   = (const float*)d_in[7];
  const float* ak   = (const float*)d_in[8];
  const float* gk   = (const float*)d_in[9];
  const float* btek = (const float*)d_in[10];
  const float* Wv   = (const float*)d_in[11];
  const float* bv   = (const float*)d_in[12];
  const float* av   = (const float*)d_in[13];
  const float* gv   = (const float*)d_in[14];
  const float* btev = (const float*)d_in[15];
  const float* Wp   = (const float*)d_in[16];
  const float* bp   = (const float*)d_in[17];
  const float* ap   = (const float*)d_in[18];
  const float* gp   = (const float*)d_in[19];
  const float* btep = (const float*)d_in[20];

  // workspace layout (bytes):
  //   Qf   bf16 [8][3072][328]   @ 0            (16,121,856)
  //   Kf   bf16 [8][3072][328]   @ 16,121,856   (16,121,856)
  //   Vf   bf16 [8][3000][1040]  @ 32,243,712   (49,920,000)  -- dead after vtrans
  //   Opt  bf16 [2][195000][64]  @ 32,243,712   (49,920,000)  -- overlays Vf
  //   Vt   bf16 [8][1152][3008]  @ 82,163,712   (55,443,456)
  //   P    bf16 [2][3072][3072]  @ 137,607,168  (37,748,736)  -- bh-pair chunks
  //   lbuf f32  [8][3072]        @ 175,355,904  (98,304)      -> total 175,454,208
  char* ws = (char*)d_ws;
  u16*   Qf   = (u16*)(ws + 0);
  u16*   Kf   = (u16*)(ws + 16121856);
  u16*   Vf   = (u16*)(ws + 32243712);
  u16*   Opt  = (u16*)(ws + 32243712);
  u16*   Vt   = (u16*)(ws + 82163712);
  u16*   P    = (u16*)(ws + 137607168);
  float* lbuf = (float*)(ws + 175355904);
  float* out  = (float*)d_out;

  qkv_kernel<<<dim3((NPT+255)/256), dim3(256), 0, stream>>>(
      x, Wq,bq,aq,gq,bteq, Wk,bk,ak,gk,btek, Wv,bv,av,gv,btev, Qf,Kf,Vf, lbuf);
  vtrans_kernel<<<dim3(47, 17, 8), dim3(256), 0, stream>>>(Vf, Vt);
  for (int c = 0; c < 4; ++c) {
    scores_kernel<<<dim3(24, 24, 2), dim3(256), 0, stream>>>(Qf, Kf, P, lbuf, c);
    pv_kernel<<<dim3(24, 9, 2), dim3(256), 0, stream>>>(P, Vt, lbuf, Opt, c);
  }
  outp_kernel<<<dim3((NPT+255)/256), dim3(256), 0, stream>>>(
      Opt, x, Wp,bp,ap,gp,btep, out);
}